// Round 3
// baseline (1127.936 us; speedup 1.0000x reference)
//
#include <hip/hip_runtime.h>
#include <math.h>

// MySimpleRNN on MI355X — fp16 hi/lo split MFMA, 16-wave blocks.
// h = tanh(x_t@wx + b + h@wh), 64 steps, B=4096, NF=128, NH=512.
// Block owns BR=16 rows; h in LDS as fp16 hi+lo; weights pre-split into
// fp16 hi/lo, pre-packed fragment-linear in d_ws. 3 MFMA products
// (hi*hi + lo*hi + hi*lo) ~ fp32-level per-step noise.
// R3: 1024 threads (16 waves, 4/SIMD) — R2's 8 waves gave only 2 waves/SIMD
// (1 block/CU by grid), latency-bound at MfmaUtil 21%.
//
// mfma_f32_16x16x32_f16 layouts (learn_hip m89/m91/m120):
//   A: lane holds A[m=lane&15][k=(lane>>4)*8+j], j=0..7
//   B: lane holds B[k=(lane>>4)*8+j][n=lane&15]
//   C/D: reg r holds C[row=(lane>>4)*4+r][col=lane&15]

#define T_STEPS 64
#define NFD     128
#define NHD     512
#define BR      16
#define THREADS 1024         // 16 waves, 4 per SIMD
#define LDH     (NHD + 8)    // padded fp16 row
#define LDX     (NFD + 8)

typedef _Float16 half8 __attribute__((ext_vector_type(8)));
typedef _Float16 half2v __attribute__((ext_vector_type(2)));
typedef float float4v __attribute__((ext_vector_type(4)));

// ---- prep: split wh/wx into fp16 hi/lo, pack fragment-linear ----
// whp index: ((ct*16 + kb)*64 + lane)*8 + j  <- wh[(kb*32 + (lane>>4)*8 + j)*512 + ct*16 + (lane&15)]
// wxp index: ((ct*4  + kb)*64 + lane)*8 + j  <- wx[(kb*32 + (lane>>4)*8 + j)*512 + ct*16 + (lane&15)]
__global__ __launch_bounds__(256) void rnn_prep(
    const float* __restrict__ wh, const float* __restrict__ wx,
    _Float16* __restrict__ whp_hi, _Float16* __restrict__ whp_lo,
    _Float16* __restrict__ wxp_hi, _Float16* __restrict__ wxp_lo)
{
    int idx = blockIdx.x * 256 + threadIdx.x;   // grid covers 262144
    {
        int j  = idx & 7;
        int l  = (idx >> 3) & 63;
        int kb = (idx >> 9) & 15;
        int ct = idx >> 13;                     // 0..31
        int k  = kb * 32 + (l >> 4) * 8 + j;
        int n  = ct * 16 + (l & 15);
        float v = wh[k * NHD + n];
        _Float16 hi = (_Float16)v;
        whp_hi[idx] = hi;
        whp_lo[idx] = (_Float16)(v - (float)hi);
    }
    if (idx < 65536) {
        int j  = idx & 7;
        int l  = (idx >> 3) & 63;
        int kb = (idx >> 9) & 3;
        int ct = idx >> 11;                     // 0..31
        int k  = kb * 32 + (l >> 4) * 8 + j;
        int n  = ct * 16 + (l & 15);
        float v = wx[k * NHD + n];
        _Float16 hi = (_Float16)v;
        wxp_hi[idx] = hi;
        wxp_lo[idx] = (_Float16)(v - (float)hi);
    }
}

// ---- main fused recurrence ----
__global__ __launch_bounds__(THREADS, 4) void rnn_mfma(
    const float* __restrict__ x,
    const float* __restrict__ bias,
    const _Float16* __restrict__ whp_hi, const _Float16* __restrict__ whp_lo,
    const _Float16* __restrict__ wxp_hi, const _Float16* __restrict__ wxp_lo,
    float* __restrict__ out)
{
    __shared__ _Float16 sh_hhi[BR * LDH];
    __shared__ _Float16 sh_hlo[BR * LDH];
    __shared__ _Float16 sh_xhi[BR * LDX];
    __shared__ _Float16 sh_xlo[BR * LDX];

    const int tid  = (int)threadIdx.x;
    const int lane = tid & 63;
    const int w    = tid >> 6;        // wave 0..15, owns cols [w*32, w*32+32)
    const int m    = lane & 15;
    const int quad = lane >> 4;
    const int row0 = (int)blockIdx.x * BR;

    for (int i = tid; i < BR * LDH; i += THREADS) {
        sh_hhi[i] = (_Float16)0.f;
        sh_hlo[i] = (_Float16)0.f;
    }

    float bv[2];
    #pragma unroll
    for (int nt = 0; nt < 2; ++nt) bv[nt] = bias[w * 32 + nt * 16 + m];

    // x staging map: 1024 threads cover 16 rows x 128 floats, 2 floats each
    const int xrow = tid >> 6;         // 0..15
    const int xcol = (tid & 63) * 2;   // 0..126
    const float* xptr = x + (row0 + xrow) * (T_STEPS * NFD) + xcol;
    float2 px = *(const float2*)xptr;

    const half8* whh = (const half8*)whp_hi;
    const half8* whl = (const half8*)whp_lo;
    const half8* wxh = (const half8*)wxp_hi;
    const half8* wxl = (const half8*)wxp_lo;

    for (int t = 0; t < T_STEPS; ++t) {
        // stage x(t): fp32 -> fp16 hi/lo
        {
            half2v vh, vl;
            float xs[2] = {px.x, px.y};
            #pragma unroll
            for (int j = 0; j < 2; ++j) {
                _Float16 hi = (_Float16)xs[j];
                vh[j] = hi;
                vl[j] = (_Float16)(xs[j] - (float)hi);
            }
            *(half2v*)&sh_xhi[xrow * LDX + xcol] = vh;
            *(half2v*)&sh_xlo[xrow * LDX + xcol] = vl;
        }
        __syncthreads();   // x staged + h(t-1) writes visible

        if (t + 1 < T_STEPS) px = *(const float2*)(xptr + (t + 1) * NFD);

        float4v acc[2];
        #pragma unroll
        for (int nt = 0; nt < 2; ++nt) {
            acc[nt][0] = bv[nt]; acc[nt][1] = bv[nt];
            acc[nt][2] = bv[nt]; acc[nt][3] = bv[nt];
        }

        // input projection: K = 128 -> 4 k-blocks of 32
        #pragma unroll
        for (int kb = 0; kb < 4; ++kb) {
            half8 ahi = *(const half8*)&sh_xhi[m * LDX + kb * 32 + quad * 8];
            half8 alo = *(const half8*)&sh_xlo[m * LDX + kb * 32 + quad * 8];
            half8 bh[2], bl[2];
            #pragma unroll
            for (int nt = 0; nt < 2; ++nt) {
                int fi = ((w * 2 + nt) * 4 + kb) * 64 + lane;
                bh[nt] = wxh[fi];
                bl[nt] = wxl[fi];
            }
            #pragma unroll
            for (int nt = 0; nt < 2; ++nt) {
                acc[nt] = __builtin_amdgcn_mfma_f32_16x16x32_f16(ahi, bh[nt], acc[nt], 0, 0, 0);
                acc[nt] = __builtin_amdgcn_mfma_f32_16x16x32_f16(alo, bh[nt], acc[nt], 0, 0, 0);
                acc[nt] = __builtin_amdgcn_mfma_f32_16x16x32_f16(ahi, bl[nt], acc[nt], 0, 0, 0);
            }
        }

        // recurrence: K = 512 -> 16 k-blocks of 32
        #pragma unroll 4
        for (int kb = 0; kb < 16; ++kb) {
            half8 ahi = *(const half8*)&sh_hhi[m * LDH + kb * 32 + quad * 8];
            half8 alo = *(const half8*)&sh_hlo[m * LDH + kb * 32 + quad * 8];
            half8 bh[2], bl[2];
            #pragma unroll
            for (int nt = 0; nt < 2; ++nt) {
                int fi = ((w * 2 + nt) * 16 + kb) * 64 + lane;
                bh[nt] = whh[fi];
                bl[nt] = whl[fi];
            }
            #pragma unroll
            for (int nt = 0; nt < 2; ++nt) {
                acc[nt] = __builtin_amdgcn_mfma_f32_16x16x32_f16(ahi, bh[nt], acc[nt], 0, 0, 0);
                acc[nt] = __builtin_amdgcn_mfma_f32_16x16x32_f16(alo, bh[nt], acc[nt], 0, 0, 0);
                acc[nt] = __builtin_amdgcn_mfma_f32_16x16x32_f16(ahi, bl[nt], acc[nt], 0, 0, 0);
            }
        }

        __syncthreads();   // all h/x reads for step t done

        // epilogue: tanh, split, write (C/D: row=quad*4+r, col=w*32+nt*16+m)
        if (t == T_STEPS - 1) {
            #pragma unroll
            for (int nt = 0; nt < 2; ++nt)
                #pragma unroll
                for (int r = 0; r < 4; ++r)
                    out[(row0 + quad * 4 + r) * NHD + w * 32 + nt * 16 + m] = tanhf(acc[nt][r]);
        } else {
            #pragma unroll
            for (int nt = 0; nt < 2; ++nt) {
                #pragma unroll
                for (int r = 0; r < 4; ++r) {
                    float v = tanhf(acc[nt][r]);
                    _Float16 hi = (_Float16)v;
                    int off = (quad * 4 + r) * LDH + w * 32 + nt * 16 + m;
                    sh_hhi[off] = hi;
                    sh_hlo[off] = (_Float16)(v - (float)hi);
                }
            }
        }
    }
}

extern "C" void kernel_launch(void* const* d_in, const int* in_sizes, int n_in,
                              void* d_out, int out_size, void* d_ws, size_t ws_size,
                              hipStream_t stream) {
    const float* x    = (const float*)d_in[0];  // [B, 64, 128]
    const float* wx   = (const float*)d_in[1];  // [128, 512]
    const float* wh   = (const float*)d_in[2];  // [512, 512]
    const float* bias = (const float*)d_in[3];  // [512]
    float* out = (float*)d_out;                 // [B, 512]

    // workspace: whp_hi 512KB | whp_lo 512KB | wxp_hi 128KB | wxp_lo 128KB
    char* ws = (char*)d_ws;
    _Float16* whp_hi = (_Float16*)(ws);
    _Float16* whp_lo = (_Float16*)(ws + 524288);
    _Float16* wxp_hi = (_Float16*)(ws + 1048576);
    _Float16* wxp_lo = (_Float16*)(ws + 1048576 + 131072);

    rnn_prep<<<1024, 256, 0, stream>>>(wh, wx, whp_hi, whp_lo, wxp_hi, wxp_lo);

    const int B = in_sizes[0] / (T_STEPS * NFD);   // 4096
    rnn_mfma<<<B / BR, THREADS, 0, stream>>>(x, bias, whp_hi, whp_lo, wxp_hi, wxp_lo, out);
}